// Round 7
// baseline (240.409 us; speedup 1.0000x reference)
//
#include <hip/hip_runtime.h>
#include <math.h>

#define SLEN 2048
#define BATCH 8
#define DMODEL 256
#define HEADS 8
#define DPROJ 128
#define DFF 1024
#define DH 16
#define MROWS (SLEN*BATCH)   // 16384

typedef unsigned short u16;
typedef unsigned int u32;
typedef __attribute__((ext_vector_type(8))) short short8;
typedef __attribute__((ext_vector_type(4))) float f32x4;
typedef __attribute__((ext_vector_type(16))) float f32x16;
typedef __attribute__((ext_vector_type(4))) unsigned short u16x4;

__device__ __forceinline__ u16 f2bf(float x) {
    union { float f; u32 u; } v; v.f = x;
    u32 r = v.u + 0x7FFFu + ((v.u >> 16) & 1u);
    return (u16)(r >> 16);
}
__device__ __forceinline__ float bf2f(u16 h) {
    union { u32 u; float f; } v; v.u = ((u32)h) << 16;
    return v.f;
}
__device__ __forceinline__ float fexp2(float x) { return __builtin_amdgcn_exp2f(x); }
// pack bf16(lo),bf16(hi) (truncating) into one dword via v_perm_b32; the
// truncation bias cancels in O/L since L is computed from the same truncated P
__device__ __forceinline__ u32 pack_bf(float lo, float hi) {
    union { float f; u32 u; } a, b; a.f = lo; b.f = hi;
    return __builtin_amdgcn_perm(b.u, a.u, 0x07060302u);
}
// async global->LDS 16B: per-lane global addr, wave-uniform LDS base
__device__ __forceinline__ void gld16(const u16* g, u16* l) {
    __builtin_amdgcn_global_load_lds(
        (const __attribute__((address_space(1))) void*)g,
        (__attribute__((address_space(3))) void*)l, 16, 0, 0);
}

// ---------------------------------------------------------------------------
// prep: src fp32->bf16 (blocks 0..4095) + weight transpose+convert (rest)
// ---------------------------------------------------------------------------
__global__ void prep_kernel(const float* __restrict__ src, u16* __restrict__ srcb,
                            const float* __restrict__ Wq, const float* __restrict__ Wk,
                            const float* __restrict__ Wv, const float* __restrict__ Wo,
                            const float* __restrict__ W1, const float* __restrict__ W2,
                            u16* __restrict__ WqT, u16* __restrict__ WkT,
                            u16* __restrict__ WvT, u16* __restrict__ WoT,
                            u16* __restrict__ W1T, u16* __restrict__ W2T) {
    if (blockIdx.x < 4096) {
        int idx = (blockIdx.x * 256 + threadIdx.x) * 4;
        float4 v = *(const float4*)(src + idx);
        u16x4 o;
        o.x = f2bf(v.x); o.y = f2bf(v.y); o.z = f2bf(v.z); o.w = f2bf(v.w);
        *(u16x4*)(srcb + idx) = o;
        return;
    }
    int i = (blockIdx.x - 4096) * 256 + threadIdx.x;
    if (i < 32768) {                       // WqT [128][256]
        int n = i >> 8, k = i & 255;
        WqT[i] = f2bf(Wq[k * 128 + n]);
    } else if (i < 65536) {
        int j = i - 32768; int n = j >> 8, k = j & 255;
        WkT[j] = f2bf(Wk[k * 128 + n]);
    } else if (i < 98304) {
        int j = i - 65536; int n = j >> 8, k = j & 255;
        WvT[j] = f2bf(Wv[k * 128 + n]);
    } else if (i < 131072) {               // WoT [256][128]
        int j = i - 98304; int n = j >> 7, k = j & 127;
        WoT[j] = f2bf(Wo[k * 256 + n]);
    } else if (i < 393216) {               // W1T [1024][256]
        int j = i - 131072; int n = j >> 8, k = j & 255;
        W1T[j] = f2bf(W1[k * 1024 + n]);
    } else if (i < 655360) {               // W2T [256][1024]
        int j = i - 393216; int n = j >> 10, k = j & 1023;
        W2T[j] = f2bf(W2[k * 256 + n]);
    }
}

// ---------------------------------------------------------------------------
// bf16 MFMA GEMM with async global->LDS staging + XOR chunk swizzle.
// ---------------------------------------------------------------------------
template<int BN, bool RELU, bool HAS_BIAS, bool OUT_BF16>
__global__ void mfma_gemm(const u16* __restrict__ A, const u16* __restrict__ BT,
                          const float* __restrict__ bias, void* __restrict__ Cout,
                          int M, int N, int K) {
    constexpr int NJ = BN / 32;
    __shared__ __align__(16) u16 As[128 * 32];
    __shared__ __align__(16) u16 Bs[BN * 32];
    const int tid = threadIdx.x;
    const int row0 = blockIdx.x * 128;
    const int col0 = blockIdx.y * BN;
    const int w = tid >> 6, l = tid & 63;
    const int wr = (w & 1) * 64, wc = (w >> 1) * (BN / 2);
    const int lcol = l & 15, lrow = (l >> 4) * 4, g = l >> 4;
    const int sl = l >> 2;
    const int swc = ((l & 3) ^ (sl & 3)) * 8;
    const int fsw = (g ^ (lcol & 3)) * 8;

    const u16* Ag0 = A + (size_t)(row0 + 16 * w + sl) * K + swc;
    const u16* Ag1 = Ag0 + (size_t)64 * K;
    const u16* Bg0 = BT + (size_t)(col0 + 16 * w + sl) * K + swc;
    const u16* Bg1 = Bg0 + (size_t)64 * K;
    u16* lA0 = As + (16 * w) * 32;
    u16* lA1 = As + (16 * w + 64) * 32;
    u16* lB0 = Bs + (16 * w) * 32;
    u16* lB1 = Bs + (16 * w + 64) * 32;

    f32x4 acc[4][NJ] = {};
    for (int k0 = 0; k0 < K; k0 += 32) {
        gld16(Ag0 + k0, lA0);
        gld16(Ag1 + k0, lA1);
        gld16(Bg0 + k0, lB0);
        if (BN == 128) gld16(Bg1 + k0, lB1);
        __syncthreads();
        short8 af[4], bf[NJ];
        #pragma unroll
        for (int i = 0; i < 4; ++i)
            af[i] = *(const short8*)(As + (wr + i * 16 + lcol) * 32 + fsw);
        #pragma unroll
        for (int j = 0; j < NJ; ++j)
            bf[j] = *(const short8*)(Bs + (wc + j * 16 + lcol) * 32 + fsw);
        #pragma unroll
        for (int i = 0; i < 4; ++i)
            #pragma unroll
            for (int j = 0; j < NJ; ++j)
                acc[i][j] = __builtin_amdgcn_mfma_f32_16x16x32_bf16(
                    af[i], bf[j], acc[i][j], 0, 0, 0);
        __syncthreads();
    }
    float bv[NJ];
    #pragma unroll
    for (int j = 0; j < NJ; ++j)
        bv[j] = HAS_BIAS ? bias[col0 + wc + j * 16 + lcol] : 0.f;
    #pragma unroll
    for (int i = 0; i < 4; ++i) {
        #pragma unroll
        for (int r = 0; r < 4; ++r) {
            size_t grow = row0 + wr + i * 16 + lrow + r;
            #pragma unroll
            for (int j = 0; j < NJ; ++j) {
                int gcol = col0 + wc + j * 16 + lcol;
                float c = acc[i][j][r] + bv[j];
                if (RELU) c = fmaxf(c, 0.f);
                if (OUT_BF16) ((u16*)Cout)[grow * N + gcol] = f2bf(c);
                else          ((float*)Cout)[grow * N + gcol] = c;
            }
        }
    }
}

// ---------------------------------------------------------------------------
// QKV MFMA GEMM -> TIGHT bf16 head-layout [bh][s][16] for q, k, v.
// q pre-scaled by 0.25*log2e.
// ---------------------------------------------------------------------------
__global__ void qkv_mfma(const u16* __restrict__ A,
                         const u16* __restrict__ WqT, const u16* __restrict__ WkT,
                         const u16* __restrict__ WvT,
                         const float* __restrict__ bq, const float* __restrict__ bk,
                         const float* __restrict__ bv,
                         u16* __restrict__ qhp, u16* __restrict__ khp,
                         u16* __restrict__ vhb) {
    const int which = blockIdx.z;
    const u16* BT   = which == 0 ? WqT : (which == 1 ? WkT : WvT);
    const float* bs = which == 0 ? bq : (which == 1 ? bk : bv);
    u16* outp       = which == 0 ? qhp : (which == 1 ? khp : vhb);
    const float scale = which == 0 ? 0.25f * 1.44269504f : 1.0f;
    __shared__ __align__(16) u16 As[128 * 32];
    __shared__ __align__(16) u16 Bs[128 * 32];
    const int tid = threadIdx.x;
    const int row0 = blockIdx.x * 128;
    const int w = tid >> 6, l = tid & 63;
    const int wr = (w & 1) * 64, wc = (w >> 1) * 64;
    const int lcol = l & 15, lrow = (l >> 4) * 4, g = l >> 4;
    const int sl = l >> 2;
    const int swc = ((l & 3) ^ (sl & 3)) * 8;
    const int fsw = (g ^ (lcol & 3)) * 8;

    const u16* Ag0 = A + (size_t)(row0 + 16 * w + sl) * DMODEL + swc;
    const u16* Ag1 = Ag0 + (size_t)64 * DMODEL;
    const u16* Bg0 = BT + (size_t)(16 * w + sl) * DMODEL + swc;
    const u16* Bg1 = Bg0 + (size_t)64 * DMODEL;
    u16* lA0 = As + (16 * w) * 32;
    u16* lA1 = As + (16 * w + 64) * 32;
    u16* lB0 = Bs + (16 * w) * 32;
    u16* lB1 = Bs + (16 * w + 64) * 32;

    f32x4 acc[4][4] = {};
    for (int k0 = 0; k0 < DMODEL; k0 += 32) {
        gld16(Ag0 + k0, lA0);
        gld16(Ag1 + k0, lA1);
        gld16(Bg0 + k0, lB0);
        gld16(Bg1 + k0, lB1);
        __syncthreads();
        short8 af[4], bf[4];
        #pragma unroll
        for (int i = 0; i < 4; ++i)
            af[i] = *(const short8*)(As + (wr + i * 16 + lcol) * 32 + fsw);
        #pragma unroll
        for (int j = 0; j < 4; ++j)
            bf[j] = *(const short8*)(Bs + (wc + j * 16 + lcol) * 32 + fsw);
        #pragma unroll
        for (int i = 0; i < 4; ++i)
            #pragma unroll
            for (int j = 0; j < 4; ++j)
                acc[i][j] = __builtin_amdgcn_mfma_f32_16x16x32_bf16(
                    af[i], bf[j], acc[i][j], 0, 0, 0);
        __syncthreads();
    }
    #pragma unroll
    for (int i = 0; i < 4; ++i) {
        #pragma unroll
        for (int r = 0; r < 4; ++r) {
            int grow = row0 + wr + i * 16 + lrow + r;
            int b = grow & 7, s = grow >> 3;
            #pragma unroll
            for (int j = 0; j < 4; ++j) {
                int gcol = wc + j * 16 + lcol;
                int h = gcol >> 4, d = gcol & 15;
                float c = acc[i][j][r] + bs[gcol];
                outp[((size_t)(b * 8 + h) * SLEN + s) * 16 + d] = f2bf(c * scale);
            }
        }
    }
}

// ---------------------------------------------------------------------------
// V transpose+augment: vhb [bh][s][16] -> va [bh][32][2048]
// rows 0..15 = V^T, row 16 = 1.0 (bf16), rows 17..31 left as-is (ignored).
// ---------------------------------------------------------------------------
__global__ void transpose_v(const u16* __restrict__ vhb, u16* __restrict__ va) {
    __shared__ u16 T[128 * 24];
    const int bh = blockIdx.y;
    const int c0 = blockIdx.x * 128;
    const int t = threadIdx.x;
    {
        int key = t >> 1, half = t & 1;
        *(uint4*)(T + key * 24 + half * 8) =
            *(const uint4*)(vhb + ((size_t)bh * SLEN + c0 + key) * 16 + half * 8);
    }
    __syncthreads();
    int d = t >> 4, k8 = (t & 15) * 8;
    u16x4 o0, o1;
    o0.x = T[(k8 + 0) * 24 + d]; o0.y = T[(k8 + 1) * 24 + d];
    o0.z = T[(k8 + 2) * 24 + d]; o0.w = T[(k8 + 3) * 24 + d];
    o1.x = T[(k8 + 4) * 24 + d]; o1.y = T[(k8 + 5) * 24 + d];
    o1.z = T[(k8 + 6) * 24 + d]; o1.w = T[(k8 + 7) * 24 + d];
    u16* dst = va + ((size_t)bh * 32 + d) * SLEN + c0 + k8;
    *(u16x4*)dst = o0;
    *(u16x4*)(dst + 4) = o1;
    if (t < 16) {   // ones row (row 16): 128 u16 per block
        u16x4 ones = { (u16)0x3F80, (u16)0x3F80, (u16)0x3F80, (u16)0x3F80 };
        u16* od = va + ((size_t)bh * 32 + 16) * SLEN + c0 + t * 8;
        *(u16x4*)od = ones;
        *(u16x4*)(od + 4) = ones;
    }
}

// ---------------------------------------------------------------------------
// MFMA flash attention v5 — 32x32x16 shapes, K=dh=16 exact (no zero-pad).
// Per 64-key tile: 2 QK MFMAs (A=K-frag m=key, B=Q-frag n=qrow, K-dim=16)
// -> D[key][q] C-layout; exp2 + v_perm pack -> P[q][key] per-wave LDS
// (stride 72 u16, 16B-aligned rows; uint2 stores 2-way=free, b128 reads
// bank-uniform); 4 PV MFMAs (A=P m=q, B=Vaug n=dh/L) with V augmented by a
// ones-row so col 16 of the accumulator IS the softmax denominator L.
// kf prefetched one tile ahead; P double-buffered; no barriers in K-loop.
// Fragment maps: A/B lane: idx=l&31, k=(l>>5)*8+j; C/D: col=l&31,
// row=(reg&3)+8*(reg>>2)+4*(l>>5) (m74/m101-verified).
// ---------------------------------------------------------------------------
__global__ __launch_bounds__(256, 4)
void attn_mfma(const u16* __restrict__ qg, const u16* __restrict__ kg,
               const u16* __restrict__ va, u16* __restrict__ ctx) {
    __shared__ __align__(16) u16 Ps[4 * 2 * 32 * 72];   // 36864 B
    const int bh = blockIdx.y;
    const int q0 = blockIdx.x * 128;
    const int tid = threadIdx.x;
    const int w = tid >> 6, l = tid & 63;
    const int n = l & 31, h5 = l >> 5;
    u16* Pbase = Ps + w * (2 * 32 * 72);

    // Q B-frag, loop-invariant: B[k=(h5*8+j)][n=qrow]
    const short8 qf = *(const short8*)(
        qg + ((size_t)bh * SLEN + q0 + w * 32 + n) * 16 + h5 * 8);
    const u16* kb = kg + (size_t)bh * SLEN * 16;
    const u16* vb = va + ((size_t)bh * 32 + n) * SLEN + h5 * 8;

    f32x16 oacc = {};   // D[m=q][n<=16: dh / L]

    short8 kf0 = *(const short8*)(kb + (size_t)n * 16 + h5 * 8);
    short8 kf1 = *(const short8*)(kb + (size_t)(32 + n) * 16 + h5 * 8);

    for (int kt = 0; kt < 32; ++kt) {
        const int k0 = kt * 64;
        u16* Pw = Pbase + (kt & 1) * (32 * 72);
        // V fragments for this tile (consumed after exp2 stage)
        short8 vf[4];
        #pragma unroll
        for (int st = 0; st < 4; ++st)
            vf[st] = *(const short8*)(vb + k0 + st * 16);
        // S^T: D[key][q]
        f32x16 z = {};
        f32x16 s0 = __builtin_amdgcn_mfma_f32_32x32x16_bf16(kf0, qf, z, 0, 0, 0);
        f32x16 s1 = __builtin_amdgcn_mfma_f32_32x32x16_bf16(kf1, qf, z, 0, 0, 0);
        // prefetch next tile's K fragments
        const int kn = (kt < 31) ? (k0 + 64) : 0;
        kf0 = *(const short8*)(kb + (size_t)(kn + n) * 16 + h5 * 8);
        kf1 = *(const short8*)(kb + (size_t)(kn + 32 + n) * 16 + h5 * 8);
        // P = exp2(S): reg quad r4 covers keys 8*r4 + 4*h5 + {0..3} (grp*32)
        #pragma unroll
        for (int r4 = 0; r4 < 4; ++r4) {
            uint2 d0, d1;
            d0.x = pack_bf(fexp2(s0[r4 * 4 + 0]), fexp2(s0[r4 * 4 + 1]));
            d0.y = pack_bf(fexp2(s0[r4 * 4 + 2]), fexp2(s0[r4 * 4 + 3]));
            d1.x = pack_bf(fexp2(s1[r4 * 4 + 0]), fexp2(s1[r4 * 4 + 1]));
            d1.y = pack_bf(fexp2(s1[r4 * 4 + 2]), fexp2(s1[r4 * 4 + 3]));
            int kbase = 8 * r4 + 4 * h5;
            *(uint2*)(Pw + n * 72 + kbase) = d0;
            *(uint2*)(Pw + n * 72 + 32 + kbase) = d1;
        }
        // O(+L) += P @ Vaug : A[m=q][k=key], B[k=key][n=dh/L]
        #pragma unroll
        for (int st = 0; st < 4; ++st) {
            short8 ap = *(const short8*)(Pw + n * 72 + st * 16 + h5 * 8);
            oacc = __builtin_amdgcn_mfma_f32_32x32x16_bf16(ap, vf[st], oacc, 0, 0, 0);
        }
    }
    // epilogue: oacc (col n = dh 0..15 / L at 16) -> Obuf[32 q][36 f32] in
    // buffer-0 region (exactly 4608 B), then normalized coalesced ctx write.
    float* Ob = (float*)Pbase;
    #pragma unroll
    for (int r = 0; r < 16; ++r) {
        int q = (r & 3) + 8 * (r >> 2) + 4 * h5;
        if (n <= 16) Ob[q * 36 + n] = oacc[r];
    }
    __syncthreads();
    const int q = l >> 1, half = l & 1;
    f32x4 o0 = *(const f32x4*)(Ob + q * 36 + half * 8);
    f32x4 o1 = *(const f32x4*)(Ob + q * 36 + half * 8 + 4);
    float rcpL = 1.0f / Ob[q * 36 + 16];
    u16x4 pa, pb;
    pa.x = f2bf(o0[0] * rcpL); pa.y = f2bf(o0[1] * rcpL);
    pa.z = f2bf(o0[2] * rcpL); pa.w = f2bf(o0[3] * rcpL);
    pb.x = f2bf(o1[0] * rcpL); pb.y = f2bf(o1[1] * rcpL);
    pb.z = f2bf(o1[2] * rcpL); pb.w = f2bf(o1[3] * rcpL);
    const int b = bh >> 3, h = bh & 7;
    const int qrow = q0 + w * 32 + q;
    u16* dst = ctx + ((size_t)qrow * BATCH + b) * DPROJ + h * DH + half * 8;
    *(u16x4*)dst = pa;
    *(u16x4*)(dst + 4) = pb;
}

// ---------------------------------------------------------------------------
// LN, wave-per-row (64 lanes x 4 elems), no barriers.
// ---------------------------------------------------------------------------
__global__ void ln1_kernel(const float* __restrict__ src, const u16* __restrict__ y,
                           const float* __restrict__ g, const float* __restrict__ bb,
                           u16* __restrict__ xb) {
    const int w = threadIdx.x >> 6, l = threadIdx.x & 63;
    const int row = blockIdx.x * 4 + w;
    const int c = l * 4;
    size_t base = (size_t)row * DMODEL;
    float4 s4 = *(const float4*)(src + base + c);
    u16x4 y4 = *(const u16x4*)(y + base + c);
    float v[4] = { s4.x + bf2f(y4.x), s4.y + bf2f(y4.y),
                   s4.z + bf2f(y4.z), s4.w + bf2f(y4.w) };
    float sum = v[0] + v[1] + v[2] + v[3];
    float ss  = v[0]*v[0] + v[1]*v[1] + v[2]*v[2] + v[3]*v[3];
    #pragma unroll
    for (int off = 1; off < 64; off <<= 1) {
        sum += __shfl_xor(sum, off);
        ss  += __shfl_xor(ss, off);
    }
    float mu = sum * (1.0f / 256.0f);
    float var = ss * (1.0f / 256.0f) - mu * mu;
    float rs = rsqrtf(var + 1e-5f);
    float4 g4 = *(const float4*)(g + c);
    float4 b4 = *(const float4*)(bb + c);
    u16x4 o;
    o.x = f2bf((v[0] - mu) * rs * g4.x + b4.x);
    o.y = f2bf((v[1] - mu) * rs * g4.y + b4.y);
    o.z = f2bf((v[2] - mu) * rs * g4.z + b4.z);
    o.w = f2bf((v[3] - mu) * rs * g4.w + b4.w);
    *(u16x4*)(xb + base + c) = o;
}

__global__ void ln2_kernel(const u16* __restrict__ x, const u16* __restrict__ f,
                           const float* __restrict__ g, const float* __restrict__ bb,
                           float* __restrict__ out) {
    const int w = threadIdx.x >> 6, l = threadIdx.x & 63;
    const int row = blockIdx.x * 4 + w;
    const int c = l * 4;
    size_t base = (size_t)row * DMODEL;
    u16x4 x4 = *(const u16x4*)(x + base + c);
    u16x4 f4 = *(const u16x4*)(f + base + c);
    float v[4] = { bf2f(x4.x) + bf2f(f4.x), bf2f(x4.y) + bf2f(f4.y),
                   bf2f(x4.z) + bf2f(f4.z), bf2f(x4.w) + bf2f(f4.w) };
    float sum = v[0] + v[1] + v[2] + v[3];
    float ss  = v[0]*v[0] + v[1]*v[1] + v[2]*v[2] + v[3]*v[3];
    #pragma unroll
    for (int off = 1; off < 64; off <<= 1) {
        sum += __shfl_xor(sum, off);
        ss  += __shfl_xor(ss, off);
    }
    float mu = sum * (1.0f / 256.0f);
    float var = ss * (1.0f / 256.0f) - mu * mu;
    float rs = rsqrtf(var + 1e-5f);
    float4 g4 = *(const float4*)(g + c);
    float4 b4 = *(const float4*)(bb + c);
    float4 o;
    o.x = (v[0] - mu) * rs * g4.x + b4.x;
    o.y = (v[1] - mu) * rs * g4.y + b4.y;
    o.z = (v[2] - mu) * rs * g4.z + b4.z;
    o.w = (v[3] - mu) * rs * g4.w + b4.w;
    *(float4*)(out + base + c) = o;
}

// ---------------------------------------------------------------------------
extern "C" void kernel_launch(void* const* d_in, const int* in_sizes, int n_in,
                              void* d_out, int out_size, void* d_ws, size_t ws_size,
                              hipStream_t stream) {
    const float* src = (const float*)d_in[0];
    const float* Wq  = (const float*)d_in[1];
    const float* bq  = (const float*)d_in[2];
    const float* Wk  = (const float*)d_in[3];
    const float* bk  = (const float*)d_in[4];
    const float* Wv  = (const float*)d_in[5];
    const float* bv  = (const float*)d_in[6];
    const float* Wo  = (const float*)d_in[7];
    const float* g1  = (const float*)d_in[8];
    const float* be1 = (const float*)d_in[9];
    const float* W1  = (const float*)d_in[10];
    const float* b1  = (const float*)d_in[11];
    const float* W2  = (const float*)d_in[12];
    const float* b2  = (const float*)d_in[13];
    const float* g2  = (const float*)d_in[14];
    const float* be2 = (const float*)d_in[15];
    char* ws = (char*)d_ws;
    float* out = (float*)d_out;

    // liveness-packed workspace (bytes), ~60 MB:
    u16* qhp  = (u16*)(ws + 0);          //  4 MB [bh][s][16]   dead after attn
    u16* khp  = (u16*)(ws + 4194304);    //  4 MB               dead after attn
    u16* vhb  = (u16*)(ws + 8388608);    //  4 MB               dead after transpose
    u16* vaug = (u16*)(ws + 12582912);   //  8 MB [bh][32][2048] dead after attn
    u16* ctxb = (u16*)(ws + 20971520);   //  4 MB               dead after Wo
    u16* yb   = (u16*)(ws + 25165824);   //  8 MB               dead after LN1
    u16* hb   = (u16*)(ws + 0);          // 32 MB  reuses all-dead 0..32M
    u16* xb   = (u16*)(ws + 33554432);   //  8 MB   live LN1 -> LN2
    u16* fb   = (u16*)(ws + 41943040);   //  8 MB   FFN2 -> LN2
    u16* srcb = (u16*)(ws + 50331648);   //  8 MB
    u16* WqT  = (u16*)(ws + 58720256);
    u16* WkT  = (u16*)(ws + 58785792);
    u16* WvT  = (u16*)(ws + 58851328);
    u16* WoT  = (u16*)(ws + 58916864);
    u16* W1T  = (u16*)(ws + 58982400);   // 512 KB
    u16* W2T  = (u16*)(ws + 59506688);   // 512 KB

    // 0) conversions (merged)
    prep_kernel<<<6656, 256, 0, stream>>>(src, srcb, Wq, Wk, Wv, Wo, W1, W2,
                                          WqT, WkT, WvT, WoT, W1T, W2T);
    // 1) QKV -> tight bf16 head layout [bh][s][16]
    qkv_mfma<<<dim3(128, 1, 3), 256, 0, stream>>>(srcb, WqT, WkT, WvT,
                                                  bq, bk, bv, qhp, khp, vhb);
    // 1b) V transpose + ones augmentation
    transpose_v<<<dim3(16, 64), 256, 0, stream>>>(vhb, vaug);
    // 2) 32x32x16 MFMA flash attention -> ctx bf16 (S*B, 128)
    attn_mfma<<<dim3(16, 64), 256, 0, stream>>>(qhp, khp, vaug, ctxb);
    // 3) yb = ctx @ Wo (bf16 out), BN=64 -> 512 blocks
    mfma_gemm<64, false, false, true><<<dim3(128, 4), 256, 0, stream>>>(
        ctxb, WoT, nullptr, yb, MROWS, DMODEL, DPROJ);
    // 4) xb = bf16(LN1(src + yb))
    ln1_kernel<<<MROWS / 4, 256, 0, stream>>>(src, yb, g1, be1, xb);
    // 5) hb = relu(xb @ W1 + b1) (bf16)
    mfma_gemm<128, true, true, true><<<dim3(128, 8), 256, 0, stream>>>(
        xb, W1T, b1, hb, MROWS, DFF, DMODEL);
    // 6) fb = hb @ W2 + b2 (bf16), BN=64 -> 512 blocks
    mfma_gemm<64, false, true, true><<<dim3(128, 4), 256, 0, stream>>>(
        hb, W2T, b2, fb, MROWS, DMODEL, DFF);
    // 7) out = LN2(xb + fb) fp32
    ln2_kernel<<<MROWS / 4, 256, 0, stream>>>(xb, fb, g2, be2, out);
}